// Round 5
// baseline (1415.037 us; speedup 1.0000x reference)
//
#include <hip/hip_runtime.h>
#include <hip/hip_bf16.h>

#define NN 50000
#define NE 800000
#define DD 128
#define NHD 16
#define EFD 16
#define RFD 64
#define KVD 336    // real K
#define KST 360    // kv/Wt row stride in bf16 elems
#define ME 64
#define HST 136    // hid bf16 row stride (272 B, 16B-aligned rows)
#define KSS 132    // k_s fp32 row stride

typedef __attribute__((ext_vector_type(8))) short bf16x8;
typedef __attribute__((ext_vector_type(4))) float f32x4;

__device__ __forceinline__ unsigned short f2bf(float f) {
    __hip_bfloat16 h = __float2bfloat16(f);   // RNE
    return __builtin_bit_cast(unsigned short, h);
}
__device__ __forceinline__ float bf2f(unsigned short u) {
    return __uint_as_float(((unsigned)u) << 16);
}

// ---------------------------------------------------------------------------
// Prep: W1s -> bf16 transposed Wt[col 0..255][k 0..359] (zeros past 335)
// ---------------------------------------------------------------------------
__global__ __launch_bounds__(256) void prep_wt(
    const float* __restrict__ xkW1, const float* __restrict__ xvW1,
    unsigned short* __restrict__ Wt)
{
    const int n = blockIdx.x;            // 0..255
    const float* W = (n < 128) ? xkW1 : xvW1;
    const int col = n & 127;
    for (int k = threadIdx.x; k < KST; k += 256) {
        float v = (k < KVD) ? W[(size_t)k * 128 + col] : 0.0f;
        Wt[(size_t)n * KST + k] = f2bf(v);
    }
}

// ---------------------------------------------------------------------------
// Prep: W2s -> bf16 transposed Wt2[n 0..143][k 0..127]
// ---------------------------------------------------------------------------
__global__ __launch_bounds__(128) void prep_wt2(
    const float* __restrict__ xkW2, const float* __restrict__ xvW2,
    unsigned short* __restrict__ Wt2)
{
    const int n = blockIdx.x;            // 0..143
    const int k = threadIdx.x;           // 0..127
    float v = (n < 128) ? xkW2[(size_t)k * 128 + n]
                        : xvW2[(size_t)k * 16 + (n - 128)];
    Wt2[(size_t)n * 128 + k] = f2bf(v);
}

// ---------------------------------------------------------------------------
// Prep: h -> bf16 copy
// ---------------------------------------------------------------------------
__global__ __launch_bounds__(256) void prep_hbf(
    const float* __restrict__ h, unsigned short* __restrict__ hb)
{
    const size_t i = ((size_t)blockIdx.x * 256 + threadIdx.x) * 4;
    const float4 f = *(const float4*)&h[i];
    ushort4 o;
    o.x = f2bf(f.x); o.y = f2bf(f.y); o.z = f2bf(f.z); o.w = f2bf(f.w);
    *(ushort4*)&hb[i] = o;
}

// ---------------------------------------------------------------------------
// Counting-sort of edges by dst: histogram -> exclusive scan -> scatter
// ---------------------------------------------------------------------------
__global__ __launch_bounds__(256) void hist_kernel(
    const int* __restrict__ dst, int* __restrict__ deg)
{
    const int i = blockIdx.x * 256 + threadIdx.x;
    if (i < NE) atomicAdd(&deg[dst[i]], 1);
}

__global__ __launch_bounds__(256) void scan_kernel(
    const int* __restrict__ deg, int* __restrict__ off, int* __restrict__ cur)
{
    __shared__ int wsum[4];
    const int t = threadIdx.x;
    const int lane = t & 63;
    const int w = t >> 6;
    int run = 0;
    for (int base = 0; base < NN; base += 256) {
        int v = (base + t < NN) ? deg[base + t] : 0;
        int x = v;
        #pragma unroll
        for (int o2 = 1; o2 < 64; o2 <<= 1) {
            int y = __shfl_up(x, o2);
            if (lane >= o2) x += y;
        }
        if (lane == 63) wsum[w] = x;
        __syncthreads();
        int pre = 0;
        #pragma unroll
        for (int ww = 0; ww < 4; ww++) if (ww < w) pre += wsum[ww];
        const int tot = wsum[0] + wsum[1] + wsum[2] + wsum[3];
        const int excl = run + pre + x - v;
        if (base + t < NN) { off[base + t] = excl; cur[base + t] = excl; }
        run += tot;
        __syncthreads();
    }
    if (t == 0) off[NN] = run;
}

__global__ __launch_bounds__(256) void scatter_kernel(
    const int* __restrict__ dst, int* __restrict__ cur, int* __restrict__ eidx)
{
    const int i = blockIdx.x * 256 + threadIdx.x;
    if (i < NE) {
        const int p = atomicAdd(&cur[dst[i]], 1);
        eidx[p] = i;
    }
}

// ---------------------------------------------------------------------------
// Kernel 1: q = MLP_xq(h), fp32 compute, bf16 output. 4 nodes / 128 threads.
// ---------------------------------------------------------------------------
__global__ __launch_bounds__(128) void qmlp_kernel(
    const float* __restrict__ h,
    const float* __restrict__ W1, const float* __restrict__ b1,
    const float* __restrict__ g,  const float* __restrict__ be,
    const float* __restrict__ W2, const float* __restrict__ b2,
    unsigned short* __restrict__ q_bf)
{
    __shared__ float hs[4][DD];
    __shared__ float hid[4][DD];
    __shared__ float red[4][2][2];
    const int j  = threadIdx.x;
    const int n0 = blockIdx.x * 4;

    #pragma unroll
    for (int n = 0; n < 4; n++) hs[n][j] = h[(size_t)(n0 + n) * DD + j];
    __syncthreads();

    float a[4];
    #pragma unroll
    for (int n = 0; n < 4; n++) a[n] = b1[j];
    #pragma unroll 8
    for (int i = 0; i < DD; i++) {
        float w = W1[i * DD + j];
        #pragma unroll
        for (int n = 0; n < 4; n++) a[n] = fmaf(hs[n][i], w, a[n]);
    }

    const int wid = j >> 6;
    #pragma unroll
    for (int n = 0; n < 4; n++) {
        float s1 = a[n], s2 = a[n] * a[n];
        #pragma unroll
        for (int off = 32; off > 0; off >>= 1) {
            s1 += __shfl_xor(s1, off);
            s2 += __shfl_xor(s2, off);
        }
        if ((j & 63) == 0) { red[n][0][wid] = s1; red[n][1][wid] = s2; }
    }
    __syncthreads();

    const float gg = g[j], bb = be[j];
    #pragma unroll
    for (int n = 0; n < 4; n++) {
        float s1   = red[n][0][0] + red[n][0][1];
        float s2   = red[n][1][0] + red[n][1][1];
        float mean = s1 * (1.0f / DD);
        float var  = s2 * (1.0f / DD) - mean * mean;
        float r    = (a[n] - mean) * rsqrtf(var + 1e-5f) * gg + bb;
        hid[n][j]  = fmaxf(r, 0.0f);
    }
    __syncthreads();

    float o[4];
    #pragma unroll
    for (int n = 0; n < 4; n++) o[n] = b2[j];
    #pragma unroll 8
    for (int i = 0; i < DD; i++) {
        float w = W2[i * DD + j];
        #pragma unroll
        for (int n = 0; n < 4; n++) o[n] = fmaf(hid[n][i], w, o[n]);
    }
    #pragma unroll
    for (int n = 0; n < 4; n++) q_bf[(size_t)(n0 + n) * DD + j] = f2bf(o[n]);
}

// ---------------------------------------------------------------------------
// Kernel 2: per-edge pipeline, 64 edges / 256 threads.
//  MODE 0: scatter via scalar f32 atomics into accN (fallback).
//  MODE 1: store per-(edge,head) payloads ex / v*ew*ex; aggregation is done
//          by gather_kernel over dst-sorted edge buckets (no f32 atomics).
// ---------------------------------------------------------------------------
union SharedU {
    unsigned short kv[ME * KST];            // 46080 B
    struct {
        unsigned short hidk[ME * HST];      // 17408 B
        unsigned short hidv[ME * HST];      // 17408 B
    } s2;
    float ks[ME * KSS];                     // 33792 B
};

template<int MODE>
__global__ __launch_bounds__(256, 3) void edge_kernel(
    const unsigned short* __restrict__ h_bf,
    const float* __restrict__ rel_x,
    const float* __restrict__ r_feat,
    const float* __restrict__ edge_feat,
    const int*   __restrict__ e_src,
    const int*   __restrict__ e_dst,
    const unsigned short* __restrict__ Wt,
    const unsigned short* __restrict__ Wt2,
    const float* __restrict__ xk_b1, const float* __restrict__ xk_g,
    const float* __restrict__ xk_be, const float* __restrict__ xk_b2,
    const float* __restrict__ xv_b1, const float* __restrict__ xv_g,
    const float* __restrict__ xv_be, const float* __restrict__ xv_W2,
    const float* __restrict__ xv_b2,
    const float* __restrict__ ew_W,  const float* __restrict__ ew_b,
    const unsigned short* __restrict__ q_bf,
    float* __restrict__ exv,      // [NE][16]  (MODE 1)
    float* __restrict__ vwe,      // [NE][16]  (MODE 1)
    float* __restrict__ accN)     // [NN][NHD][4] (MODE 0)
{
    __shared__ SharedU u;
    __shared__ float v_s[ME][NHD + 1];
    __shared__ float ew_s[ME];
    __shared__ float rel_s[ME][3];
    __shared__ int   dst_s[ME];
    __shared__ int   src_s[ME];

    const int tid = threadIdx.x;
    const int e0  = blockIdx.x * ME;

    if (tid < ME) { dst_s[tid] = e_dst[e0 + tid]; src_s[tid] = e_src[e0 + tid]; }
    else if (MODE == 0) {
        int t = tid - ME;   // 0..191
        rel_s[t / 3][t % 3] = rel_x[(size_t)e0 * 3 + t];
    }
    __syncthreads();

    // --- stage kv tile once (4 threads per edge) + e_w fused ---
    {
        const int e = tid >> 2, p = tid & 3;
        const size_t ge = (size_t)(e0 + e);
        {   // edge_feat -> cols 0..15
            float4 f = *(const float4*)&edge_feat[ge * EFD + p * 4];
            ushort4 o; o.x = f2bf(f.x); o.y = f2bf(f.y); o.z = f2bf(f.z); o.w = f2bf(f.w);
            *(ushort4*)&u.kv[e * KST + p * 4] = o;
        }
        {   // r_feat -> cols 16..79, fused ew partial dot
            float part = 0.0f;
            #pragma unroll
            for (int i = 0; i < 4; i++) {
                float4 f = *(const float4*)&r_feat[ge * RFD + p * 16 + i * 4];
                float4 w = *(const float4*)&ew_W[p * 16 + i * 4];
                part += f.x * w.x + f.y * w.y + f.z * w.z + f.w * w.w;
                ushort4 o; o.x = f2bf(f.x); o.y = f2bf(f.y); o.z = f2bf(f.z); o.w = f2bf(f.w);
                *(ushort4*)&u.kv[e * KST + 16 + p * 16 + i * 4] = o;
            }
            part += __shfl_xor(part, 1);
            part += __shfl_xor(part, 2);
            if (p == 0) ew_s[e] = 1.0f / (1.0f + __expf(-(part + ew_b[0])));
        }
        {   // h_bf[dst] -> cols 80..207
            const uint4* hp = (const uint4*)&h_bf[(size_t)dst_s[e] * DD + p * 32];
            uint4* op = (uint4*)&u.kv[e * KST + 80 + p * 32];
            #pragma unroll
            for (int i = 0; i < 4; i++) op[i] = hp[i];
        }
        {   // h_bf[src] -> cols 208..335
            const uint4* hp = (const uint4*)&h_bf[(size_t)src_s[e] * DD + p * 32];
            uint4* op = (uint4*)&u.kv[e * KST + 208 + p * 32];
            #pragma unroll
            for (int i = 0; i < 4; i++) op[i] = hp[i];
        }
        if (p < 2) {   // zero K-tail 336..351
            uint4 z = make_uint4(0, 0, 0, 0);
            *(uint4*)&u.kv[e * KST + 336 + p * 8] = z;
        }
    }
    __syncthreads();

    // --- GEMM1: MFMA. wave w: edges (w&1)*32..+31, cols (w>>1)*128..+127 ---
    const int lane = tid & 63;
    const int wv   = tid >> 6;
    const int half = wv >> 1;          // 0 = xk, 1 = xv
    const int mrow = (wv & 1) * 32;    // edge base
    const int c15  = lane & 15;
    const int q    = lane >> 4;

    f32x4 acc[2][8];
    #pragma unroll
    for (int mt = 0; mt < 2; mt++)
        #pragma unroll
        for (int nt = 0; nt < 8; nt++) acc[mt][nt] = (f32x4){0.f, 0.f, 0.f, 0.f};

    {
        const unsigned short* WtH = Wt + (size_t)(half * 128 + c15) * KST;
        const unsigned short* kvA = &u.kv[(mrow + c15) * KST];
        for (int ks = 0; ks < 11; ks++) {
            const int k0 = ks * 32 + q * 8;
            bf16x8 a0 = *(const bf16x8*)&kvA[k0];
            bf16x8 a1 = *(const bf16x8*)&kvA[16 * KST + k0];
            #pragma unroll
            for (int nt = 0; nt < 8; nt++) {
                bf16x8 b = *(const bf16x8*)&WtH[(size_t)nt * 16 * KST + k0];
                acc[0][nt] = __builtin_amdgcn_mfma_f32_16x16x32_bf16(a0, b, acc[0][nt], 0, 0, 0);
                acc[1][nt] = __builtin_amdgcn_mfma_f32_16x16x32_bf16(a1, b, acc[1][nt], 0, 0, 0);
            }
        }
    }

    // --- bias + LayerNorm + ReLU, fully in-wave (16-lane groups share a row) ---
    {
        const float* b1p = half ? xv_b1 : xk_b1;
        const float* gp  = half ? xv_g  : xk_g;
        const float* bep = half ? xv_be : xk_be;
        float bia[8], gam[8], bet[8];
        #pragma unroll
        for (int nt = 0; nt < 8; nt++) {
            int idx = nt * 16 + c15;
            bia[nt] = b1p[idx]; gam[nt] = gp[idx]; bet[nt] = bep[idx];
        }
        #pragma unroll
        for (int mt = 0; mt < 2; mt++)
            #pragma unroll
            for (int r = 0; r < 4; r++) {
                float x[8]; float s1 = 0.f, s2 = 0.f;
                #pragma unroll
                for (int nt = 0; nt < 8; nt++) {
                    x[nt] = acc[mt][nt][r] + bia[nt];
                    s1 += x[nt]; s2 = fmaf(x[nt], x[nt], s2);
                }
                #pragma unroll
                for (int off = 1; off < 16; off <<= 1) {
                    s1 += __shfl_xor(s1, off);
                    s2 += __shfl_xor(s2, off);
                }
                float mean = s1 * (1.0f / 128.0f);
                float var  = s2 * (1.0f / 128.0f) - mean * mean;
                float rstd = rsqrtf(var + 1e-5f);
                #pragma unroll
                for (int nt = 0; nt < 8; nt++)
                    acc[mt][nt][r] = fmaxf((x[nt] - mean) * rstd * gam[nt] + bet[nt], 0.0f);
            }
    }
    __syncthreads();   // all kv reads done before hid overwrites the union

    // --- store hid bf16: xk waves -> hidk, xv waves -> hidv ---
    {
        unsigned short* hdst = half ? u.s2.hidv : u.s2.hidk;
        #pragma unroll
        for (int mt = 0; mt < 2; mt++)
            #pragma unroll
            for (int r = 0; r < 4; r++) {
                const int row = mrow + mt * 16 + q * 4 + r;
                #pragma unroll
                for (int nt = 0; nt < 8; nt++)
                    hdst[row * HST + nt * 16 + c15] = f2bf(acc[mt][nt][r]);
            }
    }
    __syncthreads();

    // --- GEMM2-k via MFMA: M=64 edges, N=128, K=128 ---
    const int mb2 = (wv & 1) * 32;
    const int nb2 = (wv >> 1) * 64;
    f32x4 acck[2][4];
    #pragma unroll
    for (int mt = 0; mt < 2; mt++)
        #pragma unroll
        for (int nt = 0; nt < 4; nt++) acck[mt][nt] = (f32x4){0.f, 0.f, 0.f, 0.f};
    {
        const unsigned short* A0 = &u.s2.hidk[(mb2 + c15) * HST];
        const unsigned short* A1 = &u.s2.hidk[(mb2 + 16 + c15) * HST];
        const unsigned short* B0 = &Wt2[(size_t)(nb2 + c15) * 128];
        #pragma unroll
        for (int ks = 0; ks < 4; ks++) {
            const int k0 = ks * 32 + q * 8;
            bf16x8 a0 = *(const bf16x8*)&A0[k0];
            bf16x8 a1 = *(const bf16x8*)&A1[k0];
            #pragma unroll
            for (int nt = 0; nt < 4; nt++) {
                bf16x8 b = *(const bf16x8*)&B0[(size_t)nt * 16 * 128 + k0];
                acck[0][nt] = __builtin_amdgcn_mfma_f32_16x16x32_bf16(a0, b, acck[0][nt], 0, 0, 0);
                acck[1][nt] = __builtin_amdgcn_mfma_f32_16x16x32_bf16(a1, b, acck[1][nt], 0, 0, 0);
            }
        }
    }

    // --- v-net fp32 VALU (W2v exact), reads bf16 hidv: v[64][16] ---
    float vacc[4];
    #pragma unroll
    for (int p = 0; p < 4; p++) {
        int item = tid + p * 256;
        int e    = item >> 4;
        int col  = item & 15;
        float a = xv_b2[col];
        #pragma unroll 8
        for (int i4 = 0; i4 < 32; i4++) {
            const ushort4 hv = *(const ushort4*)&u.s2.hidv[e * HST + i4 * 4];
            a = fmaf(bf2f(hv.x), xv_W2[(i4 * 4 + 0) * 16 + col], a);
            a = fmaf(bf2f(hv.y), xv_W2[(i4 * 4 + 1) * 16 + col], a);
            a = fmaf(bf2f(hv.z), xv_W2[(i4 * 4 + 2) * 16 + col], a);
            a = fmaf(bf2f(hv.w), xv_W2[(i4 * 4 + 3) * 16 + col], a);
        }
        vacc[p] = a;
    }
    __syncthreads();   // hid reads done before ks overwrite

    // --- store k (bias folded) fp32 to LDS + v_s ---
    #pragma unroll
    for (int nt = 0; nt < 4; nt++) {
        const float bias = xk_b2[nb2 + nt * 16 + c15];
        #pragma unroll
        for (int mt = 0; mt < 2; mt++)
            #pragma unroll
            for (int r = 0; r < 4; r++)
                u.ks[(mb2 + mt * 16 + q * 4 + r) * KSS + nb2 + nt * 16 + c15] =
                    acck[mt][nt][r] + bias;
    }
    #pragma unroll
    for (int p = 0; p < 4; p++) {
        int item = tid + p * 256;
        v_s[item >> 4][item & 15] = vacc[p];
    }
    __syncthreads();

    // --- attention scores: q·k, exp; then payload store (MODE1) or atomics ---
    {
        const float inv_s8 = 0.35355339059327373f; // 1/sqrt(8)
        const int tc2  = tid & 31;
        const int te2  = tid >> 5;
        const int head = tc2 >> 1;
        const int sub  = tc2 & 1;
        #pragma unroll
        for (int e = 0; e < 8; e++) {
            int el  = te2 * 8 + e;
            int dst = dst_s[el];
            const float4  kk = *(const float4*)&u.ks[el * KSS + tc2 * 4];
            const ushort4 qb = *(const ushort4*)&q_bf[(size_t)dst * DD + tc2 * 4];
            float p = bf2f(qb.x) * kk.x + bf2f(qb.y) * kk.y +
                      bf2f(qb.z) * kk.z + bf2f(qb.w) * kk.w;
            p += __shfl_xor(p, 1);
            float ex = __expf(p * inv_s8);
            if (MODE == 1) {
                // payload store: sub0 -> ex, sub1 -> v*ew*ex (4B each, coalesced)
                if (sub == 0) {
                    exv[(size_t)(e0 + el) * NHD + head] = ex;
                } else {
                    vwe[(size_t)(e0 + el) * NHD + head] =
                        v_s[el][head] * ew_s[el] * ex;
                }
            } else {
                float vw = v_s[el][head] * ew_s[el] * ex;
                float* base = &accN[(((size_t)dst * NHD) + head) * 4];
                if (sub == 0) {
                    atomicAdd(base + 0, vw * rel_s[el][0]);
                    atomicAdd(base + 1, vw * rel_s[el][1]);
                } else {
                    atomicAdd(base + 2, vw * rel_s[el][2]);
                    atomicAdd(base + 3, ex);
                }
            }
        }
    }
}

// ---------------------------------------------------------------------------
// Gather (MODE 1): one 16-lane group per node walks its dst-sorted bucket.
// lane h owns head h; cross-head mean via shfl_xor within the group.
// ---------------------------------------------------------------------------
__global__ __launch_bounds__(256) void gather_kernel(
    const int* __restrict__ off, const int* __restrict__ eidx,
    const float* __restrict__ exv, const float* __restrict__ vwe,
    const float* __restrict__ rel_x, float* __restrict__ out)
{
    const int t = threadIdx.x;
    const int g = t >> 4;
    const int h = t & 15;
    const int n = blockIdx.x * 16 + g;
    if (n >= NN) return;
    const int j0 = off[n], j1 = off[n + 1];
    float den = 0.f, sx = 0.f, sy = 0.f, sz = 0.f;
    for (int j = j0; j < j1; j++) {
        const int e = eidx[j];
        const float ex = exv[(size_t)e * NHD + h];
        const float vw = vwe[(size_t)e * NHD + h];
        const float rx = rel_x[(size_t)e * 3 + 0];
        const float ry = rel_x[(size_t)e * 3 + 1];
        const float rz = rel_x[(size_t)e * 3 + 2];
        sx = fmaf(vw, rx, sx);
        sy = fmaf(vw, ry, sy);
        sz = fmaf(vw, rz, sz);
        den += ex;
    }
    const float c = (den > 0.f) ? 1.0f / den : 0.0f;
    float ox = sx * c, oy = sy * c, oz = sz * c;
    #pragma unroll
    for (int o2 = 1; o2 < 16; o2 <<= 1) {
        ox += __shfl_xor(ox, o2);
        oy += __shfl_xor(oy, o2);
        oz += __shfl_xor(oz, o2);
    }
    if (h == 0) {
        out[(size_t)n * 3 + 0] = ox * (1.0f / NHD);
        out[(size_t)n * 3 + 1] = oy * (1.0f / NHD);
        out[(size_t)n * 3 + 2] = oz * (1.0f / NHD);
    }
}

// ---------------------------------------------------------------------------
// Kernel 3 (MODE 0 fallback): out[n] = mean_h num[n][h]/den[n][h]
// ---------------------------------------------------------------------------
__global__ __launch_bounds__(256) void finalize_kernel(
    const float* __restrict__ accN, float* __restrict__ out)
{
    int n = blockIdx.x * blockDim.x + threadIdx.x;
    if (n >= NN) return;
    float ox = 0.0f, oy = 0.0f, oz = 0.0f;
    #pragma unroll
    for (int hh = 0; hh < NHD; hh++) {
        float4 a = *(const float4*)&accN[(((size_t)n * NHD) + hh) * 4];
        if (a.w > 0.0f) {
            float r = 1.0f / a.w;
            ox = fmaf(a.x, r, ox);
            oy = fmaf(a.y, r, oy);
            oz = fmaf(a.z, r, oz);
        }
    }
    out[n * 3 + 0] = ox * (1.0f / NHD);
    out[n * 3 + 1] = oy * (1.0f / NHD);
    out[n * 3 + 2] = oz * (1.0f / NHD);
}

extern "C" void kernel_launch(void* const* d_in, const int* in_sizes, int n_in,
                              void* d_out, int out_size, void* d_ws, size_t ws_size,
                              hipStream_t stream)
{
    const float* h         = (const float*)d_in[0];
    const float* rel_x     = (const float*)d_in[1];
    const float* r_feat    = (const float*)d_in[2];
    const float* edge_feat = (const float*)d_in[3];
    const int*   e_idx     = (const int*)d_in[4];
    const float* xk_W1 = (const float*)d_in[5];
    const float* xk_b1 = (const float*)d_in[6];
    const float* xk_g  = (const float*)d_in[7];
    const float* xk_be = (const float*)d_in[8];
    const float* xk_W2 = (const float*)d_in[9];
    const float* xk_b2 = (const float*)d_in[10];
    const float* xv_W1 = (const float*)d_in[11];
    const float* xv_b1 = (const float*)d_in[12];
    const float* xv_g  = (const float*)d_in[13];
    const float* xv_be = (const float*)d_in[14];
    const float* xv_W2 = (const float*)d_in[15];
    const float* xv_b2 = (const float*)d_in[16];
    const float* xq_W1 = (const float*)d_in[17];
    const float* xq_b1 = (const float*)d_in[18];
    const float* xq_g  = (const float*)d_in[19];
    const float* xq_be = (const float*)d_in[20];
    const float* xq_W2 = (const float*)d_in[21];
    const float* xq_b2 = (const float*)d_in[22];
    const float* ew_W  = (const float*)d_in[23];
    const float* ew_b  = (const float*)d_in[24];

    // ---- workspace layout (256B-aligned regions) ----
    size_t o = 0;
    auto take = [&](size_t bytes) -> char* {
        o = (o + 255) & ~(size_t)255;
        char* p = (char*)d_ws + o;
        o += bytes;
        return p;
    };
    unsigned short* h_bf = (unsigned short*)take((size_t)NN * DD * 2);
    unsigned short* q_bf = (unsigned short*)take((size_t)NN * DD * 2);
    unsigned short* Wt   = (unsigned short*)take((size_t)256 * KST * 2);
    unsigned short* Wt2  = (unsigned short*)take((size_t)144 * 128 * 2);
    // sorted-path regions:
    int*   deg  = (int*)take((size_t)NN * 4);
    int*   cur  = (int*)take((size_t)NN * 4);
    int*   offv = (int*)take((size_t)(NN + 1) * 4);
    int*   eidx = (int*)take((size_t)NE * 4);
    float* exv  = (float*)take((size_t)NE * NHD * 4);
    float* vwe  = (float*)take((size_t)NE * NHD * 4);
    const bool sorted = (o <= ws_size);
    // fallback region overlays the sorted-path space:
    float* accN = (float*)(void*)deg;     // NN*NHD*4 f32 = 12.8 MB

    // ---- prep (common) ----
    prep_hbf<<<(NN * DD / 4 + 255) / 256, 256, 0, stream>>>(h, h_bf);
    prep_wt<<<256, 256, 0, stream>>>(xk_W1, xv_W1, Wt);
    prep_wt2<<<144, 128, 0, stream>>>(xk_W2, xv_W2, Wt2);
    qmlp_kernel<<<NN / 4, 128, 0, stream>>>(h, xq_W1, xq_b1, xq_g, xq_be,
                                            xq_W2, xq_b2, q_bf);

    if (sorted) {
        hipMemsetAsync(deg, 0, (size_t)NN * 4, stream);
        hist_kernel<<<(NE + 255) / 256, 256, 0, stream>>>(e_idx + NE, deg);
        scan_kernel<<<1, 256, 0, stream>>>(deg, offv, cur);
        scatter_kernel<<<(NE + 255) / 256, 256, 0, stream>>>(e_idx + NE, cur, eidx);

        edge_kernel<1><<<NE / ME, 256, 0, stream>>>(
            h_bf, rel_x, r_feat, edge_feat,
            e_idx, e_idx + NE,
            Wt, Wt2,
            xk_b1, xk_g, xk_be, xk_b2,
            xv_b1, xv_g, xv_be, xv_W2, xv_b2,
            ew_W, ew_b, q_bf, exv, vwe, nullptr);

        gather_kernel<<<(NN + 15) / 16, 256, 0, stream>>>(
            offv, eidx, exv, vwe, rel_x, (float*)d_out);
    } else {
        hipMemsetAsync(accN, 0, (size_t)NN * NHD * 4 * sizeof(float), stream);
        edge_kernel<0><<<NE / ME, 256, 0, stream>>>(
            h_bf, rel_x, r_feat, edge_feat,
            e_idx, e_idx + NE,
            Wt, Wt2,
            xk_b1, xk_g, xk_be, xk_b2,
            xv_b1, xv_g, xv_be, xv_W2, xv_b2,
            ew_W, ew_b, q_bf, nullptr, nullptr, accN);

        finalize_kernel<<<(NN + 255) / 256, 256, 0, stream>>>(accN, (float*)d_out);
    }
}